// Round 5
// baseline (844.615 us; speedup 1.0000x reference)
//
#include <hip/hip_runtime.h>
#include <hip/hip_bf16.h>
#include <float.h>
#include <math.h>

// Shapes fixed by setup_inputs(): B=8, T=4096, C=1024, requested_r=2048.
constexpr int B_ = 8;
constexpr int T_ = 4096;
constexpr int C_ = 1024;
constexpr int K_ = 2048;

constexpr int BM = 128, BN = 128, BK = 32;
constexpr int NB = K_ / BN;            // 16 n-blocks
constexpr int NITER = C_ / BK;         // 32 K-chunks
// fp16 cosine-score noise sigma ~1e-5; delta = 4e-4 ~ 40 sigma.
constexpr float REFINE_DELTA = 4e-4f;

typedef _Float16 f16x8 __attribute__((ext_vector_type(8)));
typedef float    f32x4 __attribute__((ext_vector_type(4)));

__device__ __forceinline__ void gload16(const ushort* g, ushort* l) {
  __builtin_amdgcn_global_load_lds(
      (const __attribute__((address_space(1))) unsigned int*)g,
      (__attribute__((address_space(3))) unsigned int*)l, 16, 0, 0);
}

// ---------------- kernel 0: fused fp16 cast + fp64 squared norm ----------------
__global__ __launch_bounds__(256) void split_score_kernel(
    const float* __restrict__ x, ushort* __restrict__ xh,
    double* __restrict__ sd, float* __restrict__ rnorm)
{
  int row = blockIdx.x;                 // b*T + t
  size_t base = (size_t)row * C_;
  int i4 = threadIdx.x * 4;
  float4 v = *reinterpret_cast<const float4*>(&x[base + i4]);
  ushort4 h;
  { _Float16 a = (_Float16)v.x; h.x = *(ushort*)&a; }
  { _Float16 a = (_Float16)v.y; h.y = *(ushort*)&a; }
  { _Float16 a = (_Float16)v.z; h.z = *(ushort*)&a; }
  { _Float16 a = (_Float16)v.w; h.w = *(ushort*)&a; }
  *reinterpret_cast<ushort4*>(&xh[base + i4]) = h;
  double s = (double)v.x * v.x + (double)v.y * v.y
           + (double)v.z * v.z + (double)v.w * v.w;
  #pragma unroll
  for (int off = 32; off > 0; off >>= 1) s += __shfl_down(s, off);
  __shared__ double ws4[4];
  int lane = threadIdx.x & 63, wave = threadIdx.x >> 6;
  if (lane == 0) ws4[wave] = s;
  __syncthreads();
  if (threadIdx.x == 0) {
    double t = ws4[0] + ws4[1] + ws4[2] + ws4[3];
    sd[row] = t;
    rnorm[row] = (float)(1.0 / (sqrt(t) + 1e-12));
  }
}

// ---------------- kernel 2a: rank-count top-K flags + scratch zeroing ----------
__global__ __launch_bounds__(256) void rank_kernel(
    const double* __restrict__ sd, int* __restrict__ flag,
    int* __restrict__ cnt, int* __restrict__ nref)
{
  // fold scratch zeroing into this launch (grid covers B_*K_)
  int gid = (blockIdx.y * gridDim.x + blockIdx.x) * 256 + threadIdx.x;
  if (gid < B_ * K_) cnt[gid] = 0;
  if (gid == 0) *nref = 0;

  int b = blockIdx.y;
  __shared__ double sh[T_];
  for (int i = threadIdx.x; i < T_; i += 256)
    sh[i] = (i == 0) ? DBL_MAX : sd[b * T_ + i];   // CLS protection
  __syncthreads();
  int t = blockIdx.x * 128 + (threadIdx.x >> 1);
  int half = threadIdx.x & 1;
  double key = sh[t];
  int c = 0;
  int j0 = half * 2048;
  #pragma unroll 4
  for (int jj = 0; jj < 2048; jj++) {
    int j = j0 + jj;
    double sj = sh[j];
    c += (sj > key) || (sj == key && j < t);       // (score desc, idx asc)
  }
  c += __shfl_xor(c, 1);
  if (half == 0) flag[b * T_ + t] = (c < K_) ? 1 : 0;
}

// ---------------- kernel 2b: prefix over flags -> keep_idx (sorted), kpos -------
__global__ __launch_bounds__(256) void select_kernel(
    const int* __restrict__ flag, int* __restrict__ kpos, int* __restrict__ keep_idx)
{
  int b = blockIdx.x, tid = threadIdx.x;
  __shared__ int sums[256];
  int f[16], s = 0;
  int base = b * T_ + tid * 16;
  #pragma unroll
  for (int i = 0; i < 16; i++) { f[i] = flag[base + i]; s += f[i]; }
  sums[tid] = s;
  __syncthreads();
  for (int off = 1; off < 256; off <<= 1) {
    int v = 0;
    if (tid >= off) v = sums[tid - off];
    __syncthreads();
    if (tid >= off) sums[tid] += v;
    __syncthreads();
  }
  int run = (tid == 0) ? 0 : sums[tid - 1];
  #pragma unroll
  for (int i = 0; i < 16; i++) {
    int t = tid * 16 + i;
    if (f[i]) { keep_idx[b * K_ + run] = t; kpos[b * T_ + t] = run; run++; }
    else kpos[b * T_ + t] = -1;
  }
}

// ---------------- kernel 3: fp16 MFMA similarity, producer-wave staging ---------
// 5 waves: waves 0-3 compute 64x64 sub-tiles; wave 4 only issues global_load_lds
// for the next chunk. Consumers carry no outstanding VMEM, so the compiler's
// vmcnt(0)-before-barrier stalls ONLY the producer -- and that stall overlaps the
// consumers' ds_read+MFMA of the current buffer (per-wave vmcnt HW state).
__global__ __launch_bounds__(320) void mfma_argmax_kernel(
    const ushort* __restrict__ xh, const float* __restrict__ rnorm,
    const int* __restrict__ keep_idx,
    float* __restrict__ pb, float* __restrict__ ps, int* __restrict__ pk)
{
  // [stage][A/B][c-chunk 0..3][row 0..127][8 f16] = 32 KiB
  __shared__ __align__(16) ushort lds[2][2][4][128][8];

  int b  = blockIdx.z;
  int m0 = blockIdx.y * BM;
  int n0 = blockIdx.x * BN;
  int tid = threadIdx.x;
  int lane = tid & 63, wave = tid >> 6;
  int quad = lane >> 4, col = lane & 15;

  if (wave == 4) {
    // ---- producer ----
    const ushort* pa0 = xh + (size_t)(b * T_ + m0 + lane) * C_;
    const ushort* pa1 = xh + (size_t)(b * T_ + m0 + 64 + lane) * C_;
    int kt0 = keep_idx[b * K_ + n0 + lane];
    int kt1 = keep_idx[b * K_ + n0 + 64 + lane];
    const ushort* pb0 = xh + (size_t)(b * T_ + kt0) * C_;
    const ushort* pb1 = xh + (size_t)(b * T_ + kt1) * C_;

    auto issue = [&](int k0, int st) {
      ushort* l = &lds[st][0][0][0][0];     // wave-uniform base; lanes write +lane*16B
      #pragma unroll
      for (int q = 0; q < 4; q++) {
        gload16(pa0 + k0 + q * 8, l + q * 1024);          // A rows 0-63
        gload16(pa1 + k0 + q * 8, l + q * 1024 + 512);    // A rows 64-127
        gload16(pb0 + k0 + q * 8, l + 4096 + q * 1024);   // B rows 0-63
        gload16(pb1 + k0 + q * 8, l + 4096 + q * 1024 + 512);
      }
    };

    issue(0, 0);
    __syncthreads();                        // chunk 0 resident
    for (int ks = 0; ks < NITER; ks++) {
      if (ks + 1 < NITER) issue((ks + 1) * BK, (ks & 1) ^ 1);
      __syncthreads();                      // producer's vmcnt(0) overlaps consumer compute
    }
    __syncthreads();                        // epilogue stage barrier
    // final barrier below (after reduction writes) -- participate
    __syncthreads();
    return;
  }

  // ---- consumers (waves 0-3) ----
  int wm = wave >> 1, wn = wave & 1;

  float scale[4]; int ncand[4];
  #pragma unroll
  for (int j = 0; j < 4; j++) {
    int nn = n0 + wn * 64 + j * 16 + col;
    ncand[j] = nn;
    scale[j] = rnorm[b * T_ + keep_idx[b * K_ + nn]];
  }

  f32x4 acc[4][4];
  #pragma unroll
  for (int i = 0; i < 4; i++)
    #pragma unroll
    for (int j = 0; j < 4; j++) acc[i][j] = (f32x4)0.f;

  __syncthreads();                          // matches producer's post-issue(0) barrier

  for (int ks = 0; ks < NITER; ks++) {
    int cur = ks & 1;
    f16x8 fa[4], fb[4];
    #pragma unroll
    for (int i = 0; i < 4; i++) {
      int row = wm * 64 + i * 16 + col;
      fa[i] = *reinterpret_cast<const f16x8*>(&lds[cur][0][quad][row][0]);
    }
    #pragma unroll
    for (int j = 0; j < 4; j++) {
      int row = wn * 64 + j * 16 + col;
      fb[j] = *reinterpret_cast<const f16x8*>(&lds[cur][1][quad][row][0]);
    }
    #pragma unroll
    for (int i = 0; i < 4; i++)
      #pragma unroll
      for (int j = 0; j < 4; j++)
        acc[i][j] = __builtin_amdgcn_mfma_f32_16x16x32_f16(fa[i], fb[j], acc[i][j], 0, 0, 0);
    __syncthreads();
  }

  // ---- epilogue: top-2 per token row over this block's 128 centers ----
  float* redb   = (float*)(&lds[0][0][0][0][0]);   // overlay dead staging LDS
  float* redsec = redb + 256;
  int*   redk   = (int*)(redb + 512);

  // C/D layout: col=lane&15 (n), row=quad*4+reg (m)
  #pragma unroll
  for (int i = 0; i < 4; i++) {
    #pragma unroll
    for (int r = 0; r < 4; r++) {
      float b1 = -FLT_MAX, b2 = -FLT_MAX; int k1 = 0;
      #pragma unroll
      for (int j = 0; j < 4; j++) {
        float v = acc[i][j][r] * scale[j];
        if (v > b1) { b2 = b1; b1 = v; k1 = ncand[j]; }
        else if (v > b2) b2 = v;
      }
      #pragma unroll
      for (int off = 1; off < 16; off <<= 1) {
        float ob1 = __shfl_xor(b1, off);
        float ob2 = __shfl_xor(b2, off);
        int   ok1 = __shfl_xor(k1, off);
        if (ob1 > b1 || (ob1 == b1 && ok1 < k1)) { b2 = fmaxf(b1, ob2); b1 = ob1; k1 = ok1; }
        else b2 = fmaxf(b2, ob1);
      }
      if (col == 0) {
        int tl = wm * 64 + i * 16 + quad * 4 + r;
        redb[wn * 128 + tl] = b1; redsec[wn * 128 + tl] = b2; redk[wn * 128 + tl] = k1;
      }
    }
  }
  __syncthreads();
  if (tid < 128) {
    float b1 = redb[tid], b2 = redsec[tid]; int k1 = redk[tid];
    float o1 = redb[128 + tid], o2 = redsec[128 + tid]; int ok = redk[128 + tid];
    if (o1 > b1) { b2 = fmaxf(b1, o2); b1 = o1; k1 = ok; }  // ties keep lower-n wn=0
    else b2 = fmaxf(b2, o1);
    size_t p = ((size_t)(b * NB + blockIdx.x)) * T_ + m0 + tid;
    pb[p] = b1; ps[p] = b2; pk[p] = k1;
  }
  __syncthreads();   // matches producer's final barrier
}

// ---------------- kernel 3b: merge partials -> assign + refine queue + counts ---
__global__ __launch_bounds__(256) void reduce2_kernel(
    const float* __restrict__ pb, const float* __restrict__ ps, const int* __restrict__ pk,
    const float* __restrict__ rnorm, const int* __restrict__ kpos,
    int* __restrict__ assign, int* __restrict__ rlist, int* __restrict__ nref,
    int* __restrict__ cnt)
{
  int idx = blockIdx.x * 256 + threadIdx.x;   // b*T + t
  int b = idx >> 12;
  float b1 = -FLT_MAX, b2 = -FLT_MAX; int k1 = 0;
  for (int nb = 0; nb < NB; nb++) {           // nb ascending => n ascending
    size_t p = ((size_t)(b * NB + nb)) * T_ + (idx & (T_ - 1));
    float v = pb[p], s = ps[p]; int k = pk[p];
    if (v > b1) { b2 = fmaxf(b1, s); b1 = v; k1 = k; }
    else b2 = fmaxf(b2, v);
  }
  int kp = kpos[idx];
  if (kp >= 0) {
    assign[idx] = kp;
    atomicAdd(&cnt[b * K_ + kp], 1);
  } else if ((b1 - b2) * rnorm[idx] < REFINE_DELTA) {
    int qi = atomicAdd(nref, 1);
    rlist[qi] = idx;                          // refine_kernel sets assign + count
  } else {
    assign[idx] = k1;
    atomicAdd(&cnt[b * K_ + k1], 1);
  }
}

// ---------------- kernel 3c: candidate-limited fp64 re-score -------------------
__global__ __launch_bounds__(256) void refine_kernel(
    const float* __restrict__ x, const double* __restrict__ sd,
    const int* __restrict__ keep_idx, const float* __restrict__ rnorm,
    const float* __restrict__ pb, const float* __restrict__ ps, const int* __restrict__ pk,
    const int* __restrict__ nref, const int* __restrict__ rlist,
    int* __restrict__ assign, int* __restrict__ cnt)
{
  __shared__ __align__(16) float xs[C_];
  __shared__ int cand[K_];
  __shared__ int ncand_s;
  __shared__ double wv[4];
  __shared__ int wk[4];
  int n = *nref;
  int lane = threadIdx.x & 63, wave = threadIdx.x >> 6;
  for (int qi = blockIdx.x; qi < n; qi += gridDim.x) {
    int bt = rlist[qi];
    int b = bt >> 12, t = bt & (T_ - 1);
    __syncthreads();   // protect previous iteration's LDS
    const float* xt = x + ((size_t)b * T_ + t) * C_;
    for (int i = threadIdx.x; i < C_; i += 256) xs[i] = xt[i];
    if (threadIdx.x == 0) {
      float b1 = -FLT_MAX;
      for (int nb = 0; nb < NB; nb++) {
        float v = pb[((size_t)(b * NB + nb)) * T_ + t];
        if (v > b1) b1 = v;
      }
      float thr = b1 - REFINE_DELTA / rnorm[bt];   // cosine delta -> raw score units
      int nc = 0;
      for (int nb = 0; nb < NB; nb++) {
        size_t p = ((size_t)(b * NB + nb)) * T_ + t;
        if (pb[p] >= thr) {
          if (ps[p] >= thr) { for (int j = 0; j < BN; j++) cand[nc++] = nb * BN + j; }
          else cand[nc++] = pk[p];
        }
      }
      ncand_s = nc;
    }
    __syncthreads();
    int nc = ncand_s;
    double bv = -DBL_MAX; int bk = 0x7fffffff;
    for (int ci = wave; ci < nc; ci += 4) {
      int k = cand[ci];
      int kt = keep_idx[b * K_ + k];
      const float* xr = x + ((size_t)b * T_ + kt) * C_;
      double s = 0.0;
      int c0 = lane * 16;
      #pragma unroll
      for (int c = 0; c < 16; c += 4) {
        float4 v = *reinterpret_cast<const float4*>(&xr[c0 + c]);
        s += (double)xs[c0 + c]     * v.x + (double)xs[c0 + c + 1] * v.y
           + (double)xs[c0 + c + 2] * v.z + (double)xs[c0 + c + 3] * v.w;
      }
      #pragma unroll
      for (int off = 32; off > 0; off >>= 1) s += __shfl_down(s, off);
      s = __shfl(s, 0);
      s /= sqrt(sd[b * T_ + kt]);
      if (s > bv || (s == bv && k < bk)) { bv = s; bk = k; }
    }
    if (lane == 0) { wv[wave] = bv; wk[wave] = bk; }
    __syncthreads();
    if (threadIdx.x == 0) {
      double fb = wv[0]; int fk = wk[0];
      for (int w2 = 1; w2 < 4; w2++)
        if (wv[w2] > fb || (wv[w2] == fb && wk[w2] < fk)) { fb = wv[w2]; fk = wk[w2]; }
      assign[bt] = fk;
      atomicAdd(&cnt[b * K_ + fk], 1);
    }
  }
}

// ---------------- kernel 4: per-batch exclusive scan of counts ------------------
__global__ __launch_bounds__(256) void scan_kernel(
    const int* __restrict__ cnt, int* __restrict__ offs, int* __restrict__ cursor)
{
  int b = blockIdx.x, tid = threadIdx.x;
  __shared__ int sums[256];
  int v[8], s = 0;
  int base = b * K_ + tid * 8;
  #pragma unroll
  for (int i = 0; i < 8; i++) { v[i] = cnt[base + i]; s += v[i]; }
  sums[tid] = s;
  __syncthreads();
  for (int off = 1; off < 256; off <<= 1) {
    int t2 = 0;
    if (tid >= off) t2 = sums[tid - off];
    __syncthreads();
    if (tid >= off) sums[tid] += t2;
    __syncthreads();
  }
  int run = (tid == 0) ? 0 : sums[tid - 1];
  #pragma unroll
  for (int i = 0; i < 8; i++) { offs[base + i] = run; cursor[base + i] = run; run += v[i]; }
}

__global__ void scatter_kernel(const int* __restrict__ assign,
                               int* __restrict__ cursor, int* __restrict__ lists)
{
  int i = blockIdx.x * 256 + threadIdx.x;
  int b = i >> 12, t = i & (T_ - 1);
  int p = atomicAdd(&cursor[b * K_ + assign[i]], 1);
  lists[b * T_ + p] = t;
}

// ---------------- kernel 5: segment mean + alpha blend ----------------
__global__ __launch_bounds__(256) void merge_kernel(
    const float* __restrict__ x, const int* __restrict__ keep_idx,
    const int* __restrict__ cnt, const int* __restrict__ offs,
    const int* __restrict__ lists, float* __restrict__ out)
{
  int b = blockIdx.y, k = blockIdx.x;
  int m = cnt[b * K_ + k], off = offs[b * K_ + k];
  const float* xb = x + (size_t)b * T_ * C_;
  int c4 = threadIdx.x * 4;
  float sx = 0.f, sy = 0.f, sz = 0.f, sw = 0.f;
  for (int i = 0; i < m; i++) {
    int tok = lists[b * T_ + off + i];
    float4 v = *reinterpret_cast<const float4*>(&xb[(size_t)tok * C_ + c4]);
    sx += v.x; sy += v.y; sz += v.z; sw += v.w;
  }
  int kt = keep_idx[b * K_ + k];
  float4 xk = *reinterpret_cast<const float4*>(&xb[(size_t)kt * C_ + c4]);
  float fm = (float)m;
  float4 o;
  o.x = 0.85f * xk.x + 0.15f * (sx / fm);
  o.y = 0.85f * xk.y + 0.15f * (sy / fm);
  o.z = 0.85f * xk.z + 0.15f * (sz / fm);
  o.w = 0.85f * xk.w + 0.15f * (sw / fm);
  *reinterpret_cast<float4*>(&out[((size_t)b * K_ + k) * C_ + c4]) = o;
}

// ---------------- launch ----------------
extern "C" void kernel_launch(void* const* d_in, const int* in_sizes, int n_in,
                              void* d_out, int out_size, void* d_ws, size_t ws_size,
                              hipStream_t stream)
{
  const float* x = (const float*)d_in[0];
  float* out = (float*)d_out;

  char* w = (char*)d_ws;
  ushort* xh    = (ushort*)w;  w += sizeof(ushort) * (size_t)B_ * T_ * C_;  // 67 MB
  float* pb     = (float*)w;   w += sizeof(float) * (size_t)B_ * NB * T_;   // 2 MB
  float* ps     = (float*)w;   w += sizeof(float) * (size_t)B_ * NB * T_;
  int*   pk     = (int*)w;     w += sizeof(int) * (size_t)B_ * NB * T_;
  double* sd    = (double*)w;  w += sizeof(double) * B_ * T_;
  float* rnorm  = (float*)w;   w += sizeof(float) * B_ * T_;
  int* flag     = (int*)w;     w += sizeof(int) * B_ * T_;
  int* kpos     = (int*)w;     w += sizeof(int) * B_ * T_;
  int* keep_idx = (int*)w;     w += sizeof(int) * B_ * K_;
  int* assign   = (int*)w;     w += sizeof(int) * B_ * T_;
  int* cnt      = (int*)w;     w += sizeof(int) * B_ * K_;
  int* offs     = (int*)w;     w += sizeof(int) * B_ * K_;
  int* cursor   = (int*)w;     w += sizeof(int) * B_ * K_;
  int* lists    = (int*)w;     w += sizeof(int) * B_ * T_;
  int* rlist    = (int*)w;     w += sizeof(int) * B_ * T_;
  int* nref     = (int*)w;     w += 256;

  split_score_kernel<<<B_ * T_, 256, 0, stream>>>(x, xh, sd, rnorm);
  rank_kernel<<<dim3(T_ / 128, B_), 256, 0, stream>>>(sd, flag, cnt, nref);
  select_kernel<<<B_, 256, 0, stream>>>(flag, kpos, keep_idx);
  mfma_argmax_kernel<<<dim3(NB, T_ / BM, B_), 320, 0, stream>>>(
      xh, rnorm, keep_idx, pb, ps, pk);
  reduce2_kernel<<<B_ * T_ / 256, 256, 0, stream>>>(
      pb, ps, pk, rnorm, kpos, assign, rlist, nref, cnt);
  refine_kernel<<<256, 256, 0, stream>>>(
      x, sd, keep_idx, rnorm, pb, ps, pk, nref, rlist, assign, cnt);
  scan_kernel<<<B_, 256, 0, stream>>>(cnt, offs, cursor);
  scatter_kernel<<<B_ * T_ / 256, 256, 0, stream>>>(assign, cursor, lists);
  merge_kernel<<<dim3(K_, B_), 256, 0, stream>>>(x, keep_idx, cnt, offs, lists, out);
}